// Round 11
// baseline (464.534 us; speedup 1.0000x reference)
//
#include <hip/hip_runtime.h>
#include <hip/hip_cooperative_groups.h>
#include <cfloat>
#include <cmath>

#define N_Q 4096
#define N_S 1600
#define DIM 1024
#define N_C 64
#define KNN 12
#define MAX_ITER 50
#define EPS_CONV 1e-4f
#define NBLK 256         // tail_loop grid size
#define ADJ_CAP 96       // per-row LDS adjacency capacity (multiple of 8)
#define CHK 256          // av_kernel: Pt features staged per LDS chunk
#define DPAD 40          // dist_mfma LDS k-stride (f16): 32 + 8 pad -> ~2-way banks

typedef _Float16 h8 __attribute__((ext_vector_type(8)));
typedef float    f4 __attribute__((ext_vector_type(4)));

__device__ __forceinline__ float wave_max64(float v){
  #pragma unroll
  for (int o = 32; o; o >>= 1) v = fmaxf(v, __shfl_xor(v, o, 64));
  return v;
}
__device__ __forceinline__ float wave_sum64(float v){
  #pragma unroll
  for (int o = 32; o; o >>= 1) v += __shfl_xor(v, o, 64);
  return v;
}
__device__ __forceinline__ float wave_min64(float v){
  #pragma unroll
  for (int o = 32; o; o >>= 1) v = fminf(v, __shfl_xor(v, o, 64));
  return v;
}

// coherent (device-visible) element accesses for cross-block-communicated data
__device__ __forceinline__ float aload(const float* p){
  return __hip_atomic_load(p, __ATOMIC_RELAXED, __HIP_MEMORY_SCOPE_AGENT);
}
__device__ __forceinline__ void astore(float* p, float v){
  __hip_atomic_store(p, v, __ATOMIC_RELAXED, __HIP_MEMORY_SCOPE_AGENT);
}
__device__ __forceinline__ int aloadi(const int* p){
  return __hip_atomic_load(p, __ATOMIC_RELAXED, __HIP_MEMORY_SCOPE_AGENT);
}
__device__ __forceinline__ void astorei(int* p, int v){
  __hip_atomic_store(p, v, __ATOMIC_RELAXED, __HIP_MEMORY_SCOPE_AGENT);
}
__device__ __forceinline__ unsigned long long aload64(const unsigned long long* p){
  return __hip_atomic_load(p, __ATOMIC_RELAXED, __HIP_MEMORY_SCOPE_AGENT);
}
__device__ __forceinline__ void astore64(unsigned long long* p, unsigned long long v){
  __hip_atomic_store(p, v, __ATOMIC_RELAXED, __HIP_MEMORY_SCOPE_AGENT);
}

// ---- R21 fused setup kernel (unchanged): blocks 0..63 proto, 64..4159 prep.
__global__ __launch_bounds__(256) void setup_kernel(
    const float* __restrict__ fs, const int* __restrict__ ys,
    float* __restrict__ Pt, float* __restrict__ pn,
    const float* __restrict__ X, float* __restrict__ qn,
    _Float16* __restrict__ Xh, _Float16* __restrict__ Xl)
{
  __shared__ union {
    struct {                                // proto branch
      int   list[N_S];
      int   pref[256];
      int   lcount;
      float red[256];
    } p;
    float red[256];                         // prep branch
  } S;

  const int t = threadIdx.x;

  if (blockIdx.x < N_C){
    // ================= proto =================
    const int c = blockIdx.x;
    int loc[7]; int cnt = 0;
    const int base = t * 7;                  // 256*7 = 1792 >= 1600
    #pragma unroll
    for (int u = 0; u < 7; u++){
      const int i = base + u;
      if (i < N_S && ys[i] == c) loc[cnt++] = i;
    }
    S.p.pref[t] = cnt;
    __syncthreads();
    for (int off = 1; off < 256; off <<= 1){
      int v = (t >= off) ? S.p.pref[t - off] : 0;
      __syncthreads();
      S.p.pref[t] += v;
      __syncthreads();
    }
    const int start = S.p.pref[t] - cnt;
    for (int u = 0; u < cnt; u++) S.p.list[start + u] = loc[u];
    if (t == 255) S.p.lcount = S.p.pref[255];
    __syncthreads();

    const int n = S.p.lcount;
    float a0 = 0.f, a1 = 0.f, a2 = 0.f, a3 = 0.f;
    for (int m = 0; m < n; m++){
      const float* r = fs + (size_t)S.p.list[m] * DIM;
      a0 += r[t]; a1 += r[t + 256]; a2 += r[t + 512]; a3 += r[t + 768];
    }
    const float inv = 1.0f / fmaxf((float)n, 1.0f);
    const float v0 = a0*inv, v1 = a1*inv, v2 = a2*inv, v3 = a3*inv;
    Pt[(t      )*N_C + c] = v0;
    Pt[(t + 256)*N_C + c] = v1;
    Pt[(t + 512)*N_C + c] = v2;
    Pt[(t + 768)*N_C + c] = v3;
    S.p.red[t] = v0*v0 + v1*v1 + v2*v2 + v3*v3;
    __syncthreads();
    for (int o = 128; o; o >>= 1){ if (t < o) S.p.red[t] += S.p.red[t + o]; __syncthreads(); }
    if (t == 0) pn[c] = S.p.red[0];
  } else {
    // ================= prep =================
    const int i = blockIdx.x - N_C;
    const float* r = X + (size_t)i * DIM;
    const float v0 = r[t], v1 = r[t+256], v2 = r[t+512], v3 = r[t+768];
    const size_t b = (size_t)i * DIM;
    _Float16 h0 = (_Float16)v0, h1 = (_Float16)v1, h2 = (_Float16)v2, h3 = (_Float16)v3;
    Xh[b + t      ] = h0; Xl[b + t      ] = (_Float16)(v0 - (float)h0);
    Xh[b + t + 256] = h1; Xl[b + t + 256] = (_Float16)(v1 - (float)h1);
    Xh[b + t + 512] = h2; Xl[b + t + 512] = (_Float16)(v2 - (float)h2);
    Xh[b + t + 768] = h3; Xl[b + t + 768] = (_Float16)(v3 - (float)h3);
    S.red[t] = v0*v0 + v1*v1 + v2*v2 + v3*v3;
    __syncthreads();
    for (int o = 128; o; o >>= 1){ if (t < o) S.red[t] += S.red[t + o]; __syncthreads(); }
    if (t == 0) qn[i] = S.red[0];
  }
}

// ---- R23: av precompute — the former in-tail P0a, verbatim body (same
//      256x1024 geometry, same fmaf chain) -> av / d2min bit-identical.
//      Runs right after setup; frees tail of the 64KB pchunk and ~9us.
__global__ __launch_bounds__(1024) void av_kernel(
    const float* __restrict__ Xq, const float* __restrict__ Pt,
    const float* __restrict__ pn, const float* __restrict__ qn,
    float* __restrict__ avb, float* __restrict__ d2min)
{
  __shared__ float pchunk[CHK * N_C];       // 64 KB

  const int tid  = threadIdx.x;
  const int lane = tid & 63;
  const int wv   = tid >> 6;
  const int row  = blockIdx.x * 16 + wv;

  const float* xr = Xq + (size_t)row * DIM;
  const f4*    xr4 = (const f4*)xr;
  float dp[8];
  #pragma unroll
  for (int u = 0; u < 8; u++) dp[u] = 0.f;

  for (int f0 = 0; f0 < DIM; f0 += CHK){
    const f4* srcv = (const f4*)(Pt + (size_t)f0 * N_C);
    f4* dstv = (f4*)pchunk;
    #pragma unroll
    for (int u = 0; u < 4; u++) dstv[tid + u * 1024] = srcv[tid + u * 1024];
    __syncthreads();
    #pragma unroll 1
    for (int f = 0; f < CHK; f += 8){
      const f4 xa = xr4[(f0 + f) >> 2];
      const f4 xb = xr4[((f0 + f) >> 2) + 1];
      const float* pc = pchunk + f * N_C + lane;
      dp[0] = fmaf(xa[0], pc[0      ], dp[0]);
      dp[1] = fmaf(xa[1], pc[N_C    ], dp[1]);
      dp[2] = fmaf(xa[2], pc[N_C * 2], dp[2]);
      dp[3] = fmaf(xa[3], pc[N_C * 3], dp[3]);
      dp[4] = fmaf(xb[0], pc[N_C * 4], dp[4]);
      dp[5] = fmaf(xb[1], pc[N_C * 5], dp[5]);
      dp[6] = fmaf(xb[2], pc[N_C * 6], dp[6]);
      dp[7] = fmaf(xb[3], pc[N_C * 7], dp[7]);
    }
    __syncthreads();
  }
  const float dot = ((dp[0]+dp[1])+(dp[2]+dp[3])) + ((dp[4]+dp[5])+(dp[6]+dp[7]));
  const float av  = fmaxf(qn[row] + pn[lane] - 2.0f * dot, 0.0f);
  avb[row * N_C + lane] = av;
  const float d2m = wave_min64(av);
  if (lane == 0) d2min[row] = d2m;
}

// ---- pairwise distances via f16 split-precision MFMA (R22, unchanged).
__global__ __launch_bounds__(256, 2) void dist_mfma(
    const _Float16* __restrict__ Xh, const _Float16* __restrict__ Xl,
    const float* __restrict__ qn, float* __restrict__ Dq)
{
  __shared__ __align__(16) _Float16 As[2][128][DPAD];  // 20 KB
  __shared__ __align__(16) _Float16 Bs[2][256][DPAD];  // 40 KB

  const int t = threadIdx.x, w = t >> 6, l = t & 63;
  const int lb  = blockIdx.x;              // 512 blocks
  const int xcd = lb & 7, k = lb >> 3;     // round-robin XCD map, k in [0,64)
  const int bxs = xcd * 2 + (k >> 5);      // [0,16) col-panels of 256
  const int bys = k & 31;                  // [0,32) row-panels of 128
  const int bi0 = bys * 128, bj0 = bxs * 256;
  const int j0w = w * 64;                  // wave's 64-col slice
  const int fr = l & 15;
  const int kq = (l >> 4) * 8;

  const int arow = t >> 1;
  const int aseg = (t & 1) * 16;
  const int brow = t;

  f4 acc[8][4];
  #pragma unroll
  for (int a = 0; a < 8; a++)
    #pragma unroll
    for (int b = 0; b < 4; b++) acc[a][b] = (f4){0.f, 0.f, 0.f, 0.f};

  const size_t abase = (size_t)(bi0 + arow) * DIM + aseg;
  const size_t bbase = (size_t)(bj0 + brow) * DIM;

  #pragma unroll 1
  for (int k0 = 0; k0 < DIM; k0 += 32){
    h8 va0 = *(const h8*)(Xh + abase + k0);
    h8 va1 = *(const h8*)(Xh + abase + k0 + 8);
    h8 vb0 = *(const h8*)(Xl + abase + k0);
    h8 vb1 = *(const h8*)(Xl + abase + k0 + 8);
    h8 vc0 = *(const h8*)(Xh + bbase + k0);
    h8 vc1 = *(const h8*)(Xh + bbase + k0 + 8);
    h8 vc2 = *(const h8*)(Xh + bbase + k0 + 16);
    h8 vc3 = *(const h8*)(Xh + bbase + k0 + 24);
    h8 vd0 = *(const h8*)(Xl + bbase + k0);
    h8 vd1 = *(const h8*)(Xl + bbase + k0 + 8);
    h8 vd2 = *(const h8*)(Xl + bbase + k0 + 16);
    h8 vd3 = *(const h8*)(Xl + bbase + k0 + 24);
    __syncthreads();                      // prev iter's LDS reads complete
    *(h8*)&As[0][arow][aseg    ] = va0;
    *(h8*)&As[0][arow][aseg + 8] = va1;
    *(h8*)&As[1][arow][aseg    ] = vb0;
    *(h8*)&As[1][arow][aseg + 8] = vb1;
    *(h8*)&Bs[0][brow][0 ] = vc0;
    *(h8*)&Bs[0][brow][8 ] = vc1;
    *(h8*)&Bs[0][brow][16] = vc2;
    *(h8*)&Bs[0][brow][24] = vc3;
    *(h8*)&Bs[1][brow][0 ] = vd0;
    *(h8*)&Bs[1][brow][8 ] = vd1;
    *(h8*)&Bs[1][brow][16] = vd2;
    *(h8*)&Bs[1][brow][24] = vd3;
    __syncthreads();                      // tiles ready

    h8 ah[8], al[8];
    #pragma unroll
    for (int sm = 0; sm < 8; sm++){
      ah[sm] = *(const h8*)&As[0][sm * 16 + fr][kq];
      al[sm] = *(const h8*)&As[1][sm * 16 + fr][kq];
    }
    #pragma unroll
    for (int sn = 0; sn < 4; sn++){
      h8 bh = *(const h8*)&Bs[0][j0w + sn * 16 + fr][kq];
      h8 bl = *(const h8*)&Bs[1][j0w + sn * 16 + fr][kq];
      #pragma unroll
      for (int sm = 0; sm < 8; sm++){
        acc[sm][sn] = __builtin_amdgcn_mfma_f32_16x16x32_f16(ah[sm], bh, acc[sm][sn], 0, 0, 0);
        acc[sm][sn] = __builtin_amdgcn_mfma_f32_16x16x32_f16(ah[sm], bl, acc[sm][sn], 0, 0, 0);
        acc[sm][sn] = __builtin_amdgcn_mfma_f32_16x16x32_f16(al[sm], bh, acc[sm][sn], 0, 0, 0);
      }
    }
  }

  const int cr = (l >> 4) * 4;
  const int cc = l & 15;
  #pragma unroll
  for (int sm = 0; sm < 8; sm++){
    #pragma unroll
    for (int r = 0; r < 4; r++){
      const int row = bi0 + sm * 16 + cr + r;
      const float qi = qn[row];
      float* dstrow = &Dq[(size_t)row * N_Q];
      #pragma unroll
      for (int sn = 0; sn < 4; sn++){
        const int col = bj0 + j0w + sn * 16 + cc;
        float d2 = qi + qn[col] - 2.0f * acc[sm][sn][r];
        dstrow[col] = sqrtf(fmaxf(d2, 0.f));
      }
    }
  }
}

// ---- per-row 13 smallest (R21 wave-local + merge) + R23: block N_Q runs
//      the lambda-median (moved out of tail_loop where it convoyed 255
//      blocks for ~12us; here it hides under topk's 4096 tiny blocks).
//      256-thread re-lay of the median is bit-exact: fmin/fmax reductions
//      of the same value set, integer histogram + integer scan, bitonic
//      sort (data-independent network -> same sorted array), same v1/v2
//      extraction -> denom bit-identical.
__global__ __launch_bounds__(256) void topk_kernel(
    const float* __restrict__ Dq, int* __restrict__ nbr,
    float* __restrict__ dnbr, float* __restrict__ sigma,
    const float* __restrict__ d2min, float* __restrict__ denom)
{
  __shared__ int   hist[1024];
  __shared__ float cand[4096];
  __shared__ int   csum[256];
  __shared__ int   candn, b1s, b2s;
  __shared__ float cvf[4 * (KNN + 1)];
  __shared__ int   cif[4 * (KNN + 1)];

  const int i = blockIdx.x, t = threadIdx.x;
  const int lane = t & 63, w = t >> 6;

  if (i < N_Q){
    // ================= topk (R21 body) =================
    const float* row = Dq + (size_t)i * N_Q;
    float r[16];
    #pragma unroll
    for (int u = 0; u < 16; u++) r[u] = row[t + u * 256];

    float keepv = FLT_MAX; int keepi = 0x7fffffff;
    for (int s = 0; s < KNN + 1; s++){
      float best = FLT_MAX; int bj = 0x7fffffff;
      #pragma unroll
      for (int u = 0; u < 16; u++){
        float v = r[u];
        if (v < best){ best = v; bj = t + u * 256; }
      }
      #pragma unroll
      for (int o = 32; o; o >>= 1){
        float ov = __shfl_xor(best, o, 64); int oj = __shfl_xor(bj, o, 64);
        if (ov < best || (ov == best && oj < bj)){ best = ov; bj = oj; }
      }
      if (lane == s){ keepv = best; keepi = bj; }
      if ((bj & 255) == t) r[bj >> 8] = FLT_MAX;
    }
    if (lane < KNN + 1){ cvf[w * (KNN + 1) + lane] = keepv; cif[w * (KNN + 1) + lane] = keepi; }
    __syncthreads();

    if (w == 0){
      float mv = FLT_MAX; int mi = 0x7fffffff;
      if (lane < 4 * (KNN + 1)){ mv = cvf[lane]; mi = cif[lane]; }
      for (int s = 0; s < KNN + 1; s++){
        float best = mv; int bj = mi;
        #pragma unroll
        for (int o = 32; o; o >>= 1){
          float ov = __shfl_xor(best, o, 64); int oj = __shfl_xor(bj, o, 64);
          if (ov < best || (ov == best && oj < bj)){ best = ov; bj = oj; }
        }
        if (lane == 0){
          if (s >= 1){ nbr[i*KNN + s - 1] = bj; dnbr[i*KNN + s - 1] = best; }
          if (s == KNN) sigma[i] = best + 1e-8f;
        }
        if (mi == bj) mv = FLT_MAX;
      }
    }
  } else {
    // ================= lambda-median (256-thread re-lay) =================
    float dv[16];
    int   bidx[16];
    #pragma unroll
    for (int u = 0; u < 16; u++) dv[u] = sqrtf(aload(&d2min[t * 16 + u]));
    float mn = dv[0], mx = dv[0];
    #pragma unroll
    for (int u = 1; u < 16; u++){ mn = fminf(mn, dv[u]); mx = fmaxf(mx, dv[u]); }
    mn = wave_min64(mn); mx = wave_max64(mx);
    if (lane == 0){ cand[w] = mn; cand[w + 4] = mx; }
    __syncthreads();
    if (t == 0){
      float a = cand[0], b = cand[4];
      for (int k = 1; k < 4; k++){ a = fminf(a, cand[k]); b = fmaxf(b, cand[4 + k]); }
      cand[8] = a; cand[9] = b;
    }
    __syncthreads();
    mn = cand[8]; mx = cand[9];
    const float rng = mx - mn;
    const float scale = (rng > 0.f) ? (1024.0f / rng) : 0.f;
    #pragma unroll
    for (int u = 0; u < 4; u++) hist[t * 4 + u] = 0;
    __syncthreads();
    #pragma unroll
    for (int u = 0; u < 16; u++){
      int b = (int)((dv[u] - mn) * scale);
      b = b < 0 ? 0 : (b > 1023 ? 1023 : b);
      bidx[u] = b;
      atomicAdd(&hist[b], 1);
    }
    __syncthreads();
    // inclusive prefix over 1024 bins with 256 threads (exact integer scan)
    int h0 = hist[t*4], h1 = hist[t*4+1], h2 = hist[t*4+2], h3 = hist[t*4+3];
    const int s4 = h0 + h1 + h2 + h3;
    csum[t] = s4;
    __syncthreads();
    for (int off = 1; off < 256; off <<= 1){
      int v = (t >= off) ? csum[t - off] : 0;
      __syncthreads();
      csum[t] += v;
      __syncthreads();
    }
    int run = csum[t] - s4;
    hist[t*4    ] = run + h0;
    hist[t*4 + 1] = run + h0 + h1;
    hist[t*4 + 2] = run + h0 + h1 + h2;
    hist[t*4 + 3] = run + h0 + h1 + h2 + h3;
    __syncthreads();
    #pragma unroll
    for (int u = 0; u < 4; u++){
      const int b = t * 4 + u;
      if (hist[b] >= 2048 && (b == 0 || hist[b - 1] < 2048)) b1s = b;
      if (hist[b] >= 2049 && (b == 0 || hist[b - 1] < 2049)) b2s = b;
    }
    if (t == 0) candn = 0;
    __syncthreads();
    const int b1 = b1s, b2 = b2s;
    const int cntBefore = (b1 > 0) ? hist[b1 - 1] : 0;
    #pragma unroll
    for (int u = 0; u < 16; u++){
      if (bidx[u] >= b1 && bidx[u] <= b2){
        int pos = atomicAdd(&candn, 1);
        cand[pos] = dv[u];
      }
    }
    __syncthreads();
    const int mcnt = candn;
    int P = 2; while (P < mcnt) P <<= 1;
    for (int i2 = mcnt + t; i2 < P; i2 += 256) cand[i2] = FLT_MAX;
    __syncthreads();
    for (int k = 2; k <= P; k <<= 1){
      for (int st = k >> 1; st > 0; st >>= 1){
        for (int i2 = t; i2 < P; i2 += 256){
          int j2 = i2 ^ st;
          if (j2 > i2){
            float a2 = cand[i2], b3 = cand[j2];
            bool up = ((i2 & k) == 0);
            if (up ? (a2 > b3) : (a2 < b3)){ cand[i2] = b3; cand[j2] = a2; }
          }
        }
        __syncthreads();
      }
    }
    if (t == 0){
      float v1 = cand[2047 - cntBefore], v2 = cand[2048 - cntBefore];
      float med = 0.5f * (v1 + v2);
      astore(denom, 2.0f * med * med + 1e-8f);
    }
  }
}

// ============ hierarchical monotonic grid barrier (setup phases only) ============
__device__ __forceinline__ void gbar_leader(int* garr, int* gcnt, int* gen, int target){
  const int g = blockIdx.x >> 4;
  int old = __hip_atomic_fetch_add(&garr[g * 32], 1, __ATOMIC_RELAXED, __HIP_MEMORY_SCOPE_AGENT);
  if ((old & 15) == 15){
    int o2 = __hip_atomic_fetch_add(gcnt, 1, __ATOMIC_RELAXED, __HIP_MEMORY_SCOPE_AGENT);
    if ((o2 & 15) == 15)
      __hip_atomic_fetch_add(gen, 1, __ATOMIC_RELAXED, __HIP_MEMORY_SCOPE_AGENT);
  }
  while (__hip_atomic_load(gen, __ATOMIC_RELAXED, __HIP_MEMORY_SCOPE_AGENT) < target)
    __builtin_amdgcn_s_sleep(1);
}

// ============ packed {phase, delta} flag barrier — contiguous 8B slots ============
__device__ __forceinline__ void pbar_wave0(
    unsigned long long* pslot, int ph, int* sdm, float* sdelta_sh, int lane)
{
  const int par = ph & 1;
  unsigned long long* base = pslot + (size_t)par * NBLK;
  if (lane == 0){
    int myd = sdm[par]; sdm[par] = 0;
    unsigned long long pack =
        ((unsigned long long)(unsigned int)myd << 32) | (unsigned int)ph;
    __builtin_amdgcn_s_waitcnt(0);          // all prior y stores drained
    astore64(&base[blockIdx.x], pack);
  }
  int mx;
  while (1){
    unsigned long long v0 = aload64(&base[lane      ]);
    unsigned long long v1 = aload64(&base[lane +  64]);
    unsigned long long v2 = aload64(&base[lane + 128]);
    unsigned long long v3 = aload64(&base[lane + 192]);
    int f0 = (int)(unsigned int)v0, f1 = (int)(unsigned int)v1;
    int f2 = (int)(unsigned int)v2, f3 = (int)(unsigned int)v3;
    int mn = f0 < f1 ? f0 : f1;
    mn = f2 < mn ? f2 : mn;
    mn = f3 < mn ? f3 : mn;
    if (__all(mn >= ph)){
      int d0 = (int)(v0 >> 32), d1 = (int)(v1 >> 32);
      int d2 = (int)(v2 >> 32), d3 = (int)(v3 >> 32);
      mx = d0 > d1 ? d0 : d1;
      mx = d2 > mx ? d2 : mx;
      mx = d3 > mx ? d3 : mx;
      break;
    }
    __builtin_amdgcn_s_sleep(1);
  }
  #pragma unroll
  for (int o = 32; o; o >>= 1){ int ox = __shfl_xor(mx, o, 64); mx = ox > mx ? ox : mx; }
  if (lane == 0) *sdelta_sh = __int_as_float(mx);
}

// ---- chunked SpMV (R17): K groups of 8 edges, all loads issue concurrently,
//      then the fma sequence runs in the exact old order.
template<int K>
__device__ __forceinline__ void chunk_fma(
    const float* __restrict__ src, const int2* adj, int gbase, int lane,
    float& s0, float& s1, float& s2, float& s3,
    float& s4, float& s5, float& s6, float& s7)
{
  float yv[K][8], wv[K][8];
  #pragma unroll
  for (int g = 0; g < K; g++){
    #pragma unroll
    for (int u = 0; u < 8; u++){
      int2 a = adj[(gbase + g) * 8 + u];
      wv[g][u] = __int_as_float(a.y);
      yv[g][u] = aload(&src[a.x + lane]);
    }
  }
  #pragma unroll
  for (int g = 0; g < K; g++){
    s0 = fmaf(wv[g][0], yv[g][0], s0);
    s1 = fmaf(wv[g][1], yv[g][1], s1);
    s2 = fmaf(wv[g][2], yv[g][2], s2);
    s3 = fmaf(wv[g][3], yv[g][3], s3);
    s4 = fmaf(wv[g][4], yv[g][4], s4);
    s5 = fmaf(wv[g][5], yv[g][5], s5);
    s6 = fmaf(wv[g][6], yv[g][6], s6);
    s7 = fmaf(wv[g][7], yv[g][7], s7);
  }
}

__device__ __forceinline__ float spmv_row(
    const float* __restrict__ src, const int2* adj,
    const int* __restrict__ colA, const float* __restrict__ wA,
    int p0, int p1v, int lane)
{
  const int deg  = p1v - p0;
  const int ncap = deg < ADJ_CAP ? deg : ADJ_CAP;
  const int nfull = ncap & ~7;
  const int ng = nfull >> 3;
  float s0=0.f,s1=0.f,s2=0.f,s3=0.f,s4=0.f,s5=0.f,s6=0.f,s7=0.f;

  int g = 0;
  #pragma unroll 1
  for (; g + 4 <= ng; g += 4){
    chunk_fma<4>(src, adj, g, lane, s0,s1,s2,s3,s4,s5,s6,s7);
  }
  {
    const int left = ng - g;
    if (left == 3)      chunk_fma<3>(src, adj, g, lane, s0,s1,s2,s3,s4,s5,s6,s7);
    else if (left == 2) chunk_fma<2>(src, adj, g, lane, s0,s1,s2,s3,s4,s5,s6,s7);
    else if (left == 1) chunk_fma<1>(src, adj, g, lane, s0,s1,s2,s3,s4,s5,s6,s7);
  }

  if (deg > ADJ_CAP){
    int qg = p0 + ADJ_CAP;
    for (; qg + 8 <= p1v; qg += 8){
      s0 = fmaf(wA[qg    ], aload(&src[colA[qg    ] + lane]), s0);
      s1 = fmaf(wA[qg + 1], aload(&src[colA[qg + 1] + lane]), s1);
      s2 = fmaf(wA[qg + 2], aload(&src[colA[qg + 2] + lane]), s2);
      s3 = fmaf(wA[qg + 3], aload(&src[colA[qg + 3] + lane]), s3);
      s4 = fmaf(wA[qg + 4], aload(&src[colA[qg + 4] + lane]), s4);
      s5 = fmaf(wA[qg + 5], aload(&src[colA[qg + 5] + lane]), s5);
      s6 = fmaf(wA[qg + 6], aload(&src[colA[qg + 6] + lane]), s6);
      s7 = fmaf(wA[qg + 7], aload(&src[colA[qg + 7] + lane]), s7);
    }
    for (; qg < p1v; qg++)
      s0 = fmaf(wA[qg], aload(&src[colA[qg] + lane]), s0);
  } else {
    const int rem = deg - nfull;            // 0..7
    if (rem > 0){
      float yr[7], wr[7];
      #pragma unroll
      for (int u = 0; u < 7; u++){
        if (u < rem){
          int2 a = adj[nfull + u];
          wr[u] = __int_as_float(a.y);
          yr[u] = aload(&src[a.x + lane]);
        }
      }
      #pragma unroll
      for (int u = 0; u < 7; u++)
        if (u < rem) s0 = fmaf(wr[u], yr[u], s0);
    }
  }
  return ((s0+s1)+(s2+s3)) + ((s4+s5)+(s6+s7));
}

// ---- fused tail. R23: P0a moved to av_kernel (av loaded back, d2m
//      recomputed via the same wave_min64 -> identical bits); median moved
//      to topk (denom read across kernel boundary). Loop structure (R17)
//      untouched. LDS 78KB -> ~17KB.
__global__ __launch_bounds__(1024, 4) void tail_loop(
    const float* __restrict__ avb,
    const int* __restrict__ nbr, const float* __restrict__ dnbr,
    const float* __restrict__ sigma,
    float* denom, float* wh,
    float* rowsum, int* indeg, int* rowptr, int* fillc,
    int* colA, float* wA, float* buf0, float* buf1,
    unsigned long long* pslot,
    int* gcnt, int* gen, int* garr, int* __restrict__ out)
{
  __shared__ int   sdm[2];
  __shared__ float sdelta;
  __shared__ int   ipart[1024];
  __shared__ int2  adjL[16 * ADJ_CAP];      // 12 KB, per-wave adjacency

  const int tid  = threadIdx.x;
  const int lane = tid & 63;
  const int wv   = tid >> 6;
  const int row  = blockIdx.x * 16 + wv;
  if (tid == 0){ sdm[0] = 0; sdm[1] = 0; }

  // ---------- load av (bit-exact f32 round-trip from av_kernel) ----------
  const float av  = avb[row * N_C + lane];
  const float d2m = wave_min64(av);        // same reduction as before

  // ---------- P0b: edge weights + degrees ----------
  const int e = blockIdx.x * 1024 + tid;
  if (e < N_Q * KNN){
    const int i = e / KNN;
    const int j = nbr[e];
    float wgt = 0.5f * expf(-dnbr[e] / (sigma[i] * sigma[j]));
    astore(&wh[e], wgt);
    atomicAdd(&rowsum[i], wgt);
    atomicAdd(&rowsum[j], wgt);
    atomicAdd(&indeg[j], 1);
  }

  __syncthreads();
  if (tid == 0) gbar_leader(garr, gcnt, gen, 1);
  __syncthreads();

  // ---------- P1: y0 + scan (block 0) ----------
  float xv = -av;
  float m = wave_max64(xv), ee = expf(xv - m), ss = wave_sum64(ee);
  float prev = ee / ss;                    // y0
  astore(&buf0[row * N_C + lane], prev);

  if (blockIdx.x == 0){
    const int base = tid * 4;
    int c0 = aloadi(&indeg[base]),     c1 = aloadi(&indeg[base + 1]);
    int c2 = aloadi(&indeg[base + 2]), c3 = aloadi(&indeg[base + 3]);
    const int s4 = c0 + c1 + c2 + c3;
    ipart[tid] = s4;
    __syncthreads();
    for (int off = 1; off < 1024; off <<= 1){
      int v = (tid >= off) ? ipart[tid - off] : 0;
      __syncthreads();
      ipart[tid] += v;
      __syncthreads();
    }
    int run = ipart[tid] - s4;
    astorei(&rowptr[base    ], KNN * (base    ) + run); run += c0;
    astorei(&rowptr[base + 1], KNN * (base + 1) + run); run += c1;
    astorei(&rowptr[base + 2], KNN * (base + 2) + run); run += c2;
    astorei(&rowptr[base + 3], KNN * (base + 3) + run);
    if (tid == 1023) astorei(&rowptr[N_Q], KNN * N_Q + ipart[1023]);
  }

  __syncthreads();
  if (tid == 0) gbar_leader(garr, gcnt, gen, 2);
  __syncthreads();

  // ---------- P2: CSR fill + per-row coef ----------
  if (e < N_Q * KNN){
    const int i = e / KNN, tt = e % KNN;
    const int j = nbr[e];
    const float wgt = aload(&wh[e]);
    const int p = aloadi(&rowptr[i]) + tt;
    colA[p] = j * N_C; wA[p] = wgt;
    const int q = aloadi(&rowptr[j]) + KNN + atomicAdd(&fillc[j], 1);
    colA[q] = i * N_C; wA[q] = wgt;
  }
  const float cf = expf(-d2m / aload(denom)) / (aload(&rowsum[row]) + 1e-8f);
  const int p0  = aloadi(&rowptr[row]);
  const int p1v = aloadi(&rowptr[row + 1]);

  __builtin_amdgcn_fence(__ATOMIC_RELEASE, "agent");
  __syncthreads();
  if (tid == 0) gbar_leader(garr, gcnt, gen, 3);
  __syncthreads();
  __builtin_amdgcn_fence(__ATOMIC_ACQUIRE, "agent");

  // ---------- preload loop-invariant adjacency into LDS ----------
  {
    const int deg  = p1v - p0;
    const int ncap = deg < ADJ_CAP ? deg : ADJ_CAP;
    for (int u = lane; u < ncap; u += 64)
      adjL[wv * ADJ_CAP + u] = make_int2(colA[p0 + u], __float_as_int(wA[p0 + u]));
  }
  __syncthreads();
  const int2* adj = adjL + wv * ADJ_CAP;

  // ---------- P3: y1 = step(y0); publish delta via pbar phase 1 ----------
  float cur;
  {
    float sum = spmv_row(buf0, adj, colA, wA, p0, p1v, lane);
    float xv2 = -av + cf * sum;
    float mm = wave_max64(xv2), e2 = expf(xv2 - mm), ss2 = wave_sum64(e2);
    cur = e2 / ss2;
    astore(&buf1[row * N_C + lane], cur);
  }
  float dm = wave_max64(fabsf(cur - prev));
  if (lane == 0) atomicMax(&sdm[1], __float_as_int(dm));
  __syncthreads();                         // drains all waves' y stores + LDS
  if (wv == 0) pbar_wave0(pslot, 1, sdm, &sdelta, lane);
  __syncthreads();
  float delta = sdelta;

  // ---------- P4: the while-loop ----------
  int par = 1;                             // buffer currently holding y_new
  for (int t = 0;; t++){
    if (t >= MAX_ITER || delta < EPS_CONV) break;
    const float* src = par ? buf1 : buf0;
    float*       dst = par ? buf0 : buf1;
    float sum = spmv_row(src, adj, colA, wA, p0, p1v, lane);
    float xv2 = -av + cf * sum;
    float mm = wave_max64(xv2), e2 = expf(xv2 - mm), ss2 = wave_sum64(e2);
    float nxt = e2 / ss2;
    astore(&dst[row * N_C + lane], nxt);
    const int ph = t + 2;
    dm = wave_max64(fabsf(nxt - cur));
    if (lane == 0) atomicMax(&sdm[ph & 1], __float_as_int(dm));
    __syncthreads();
    if (wv == 0) pbar_wave0(pslot, ph, sdm, &sdelta, lane);
    __syncthreads();
    delta = sdelta;
    prev = cur; cur = nxt; par ^= 1;
  }

  // argmax of y (prev); first occurrence on ties
  float bv = prev; int bi = lane;
  #pragma unroll
  for (int o = 32; o; o >>= 1){
    float ov = __shfl_xor(bv, o, 64); int oi = __shfl_xor(bi, o, 64);
    if (ov > bv || (ov == bv && oi < bi)){ bv = ov; bi = oi; }
  }
  if (lane == 0) out[row] = bi;
}

extern "C" void kernel_launch(void* const* d_in, const int* in_sizes, int n_in,
                              void* d_out, int out_size, void* d_ws, size_t ws_size,
                              hipStream_t stream)
{
  const float* feat_s = (const float*)d_in[0];
  const int*   y_s    = (const int*)d_in[1];
  const float* feat_q = (const float*)d_in[2];
  int* out = (int*)d_out;

  char* wp = (char*)d_ws;
  auto alloc = [&](size_t bytes) -> char* {
    char* p = wp;
    wp += (bytes + 255) & ~(size_t)255;
    return p;
  };
  float*     Dq  = (float*)alloc((size_t)N_Q * N_Q * 4);     // 64 MB
  _Float16*  Xh  = (_Float16*)alloc((size_t)N_Q * DIM * 2);  // 8 MB
  _Float16*  Xl  = (_Float16*)alloc((size_t)N_Q * DIM * 2);  // 8 MB
  float* Pt     = (float*)alloc((size_t)DIM * N_C * 4);
  float* pn     = (float*)alloc(N_C * 4);
  float* qn     = (float*)alloc(N_Q * 4);
  float* avb    = (float*)alloc((size_t)N_Q * N_C * 4);      // 1 MB
  float* d2min  = (float*)alloc(N_Q * 4);
  float* denom  = (float*)alloc(256);
  int*   nbr    = (int*)alloc((size_t)N_Q * KNN * 4);
  float* dnbr   = (float*)alloc((size_t)N_Q * KNN * 4);
  float* sigma  = (float*)alloc(N_Q * 4);
  float* wh     = (float*)alloc((size_t)N_Q * KNN * 4);
  int*   rowptr = (int*)alloc((N_Q + 1) * 4);
  int*   colA   = (int*)alloc((size_t)2 * N_Q * KNN * 4);
  float* wA     = (float*)alloc((size_t)2 * N_Q * KNN * 4);
  float* buf0   = (float*)alloc((size_t)N_Q * N_C * 4);
  float* buf1   = (float*)alloc((size_t)N_Q * N_C * 4);
  // zero-region: rowsum | indeg | fillc | syncw | garr | pslot (packed, 4KB)
  const size_t zbytes = (size_t)N_Q*12 + 256 + 2048 + 2 * NBLK * 8;
  char*  zbase  = alloc(zbytes);
  float* rowsum = (float*)(zbase);
  int*   indeg  = (int*)(zbase + N_Q*4);
  int*   fillc  = (int*)(zbase + N_Q*8);
  int*   syncw  = (int*)(zbase + N_Q*12);
  int*   garr   = (int*)(zbase + N_Q*12 + 256);
  unsigned long long* pslot = (unsigned long long*)(zbase + N_Q*12 + 256 + 2048);

  hipMemsetAsync(zbase, 0, zbytes, stream);

  setup_kernel <<<N_Q + N_C, 256, 0, stream>>>(feat_s, y_s, Pt, pn, feat_q, qn, Xh, Xl);
  av_kernel    <<<NBLK, 1024, 0, stream>>>(feat_q, Pt, pn, qn, avb, d2min);
  dist_mfma    <<<512, 256, 0, stream>>>(Xh, Xl, qn, Dq);
  topk_kernel  <<<N_Q + 1, 256, 0, stream>>>(Dq, nbr, dnbr, sigma, d2min, denom);

  int* gcnt = &syncw[0];
  int* gen  = &syncw[32];
  void* args[] = {&avb, &nbr, &dnbr, &sigma,
                  &denom, &wh, &rowsum, &indeg, &rowptr, &fillc,
                  &colA, &wA, &buf0, &buf1, &pslot,
                  &gcnt, &gen, &garr, &out};
  hipLaunchCooperativeKernel((void*)tail_loop, dim3(NBLK), dim3(1024), args, 0, stream);
}

// Round 12
// 454.961 us; speedup vs baseline: 1.0210x; 1.0210x over previous
//
#include <hip/hip_runtime.h>
#include <hip/hip_cooperative_groups.h>
#include <cfloat>
#include <cmath>

#define N_Q 4096
#define N_S 1600
#define DIM 1024
#define N_C 64
#define KNN 12
#define MAX_ITER 50
#define EPS_CONV 1e-4f
#define NBLK 256         // tail_loop grid size
#define ADJ_CAP 96       // per-row LDS adjacency capacity (multiple of 8)
#define CHK 256          // av_kernel: Pt features staged per LDS chunk
#define DPAD 40          // dist_mfma LDS k-stride (f16): 32 + 8 pad

typedef _Float16 h8 __attribute__((ext_vector_type(8)));
typedef float    f4 __attribute__((ext_vector_type(4)));

__device__ __forceinline__ float wave_max64(float v){
  #pragma unroll
  for (int o = 32; o; o >>= 1) v = fmaxf(v, __shfl_xor(v, o, 64));
  return v;
}
__device__ __forceinline__ float wave_sum64(float v){
  #pragma unroll
  for (int o = 32; o; o >>= 1) v += __shfl_xor(v, o, 64);
  return v;
}
__device__ __forceinline__ float wave_min64(float v){
  #pragma unroll
  for (int o = 32; o; o >>= 1) v = fminf(v, __shfl_xor(v, o, 64));
  return v;
}

// coherent (device-visible) element accesses for cross-block-communicated data
__device__ __forceinline__ float aload(const float* p){
  return __hip_atomic_load(p, __ATOMIC_RELAXED, __HIP_MEMORY_SCOPE_AGENT);
}
__device__ __forceinline__ void astore(float* p, float v){
  __hip_atomic_store(p, v, __ATOMIC_RELAXED, __HIP_MEMORY_SCOPE_AGENT);
}
__device__ __forceinline__ int aloadi(const int* p){
  return __hip_atomic_load(p, __ATOMIC_RELAXED, __HIP_MEMORY_SCOPE_AGENT);
}
__device__ __forceinline__ void astorei(int* p, int v){
  __hip_atomic_store(p, v, __ATOMIC_RELAXED, __HIP_MEMORY_SCOPE_AGENT);
}
__device__ __forceinline__ unsigned long long aload64(const unsigned long long* p){
  return __hip_atomic_load(p, __ATOMIC_RELAXED, __HIP_MEMORY_SCOPE_AGENT);
}
__device__ __forceinline__ void astore64(unsigned long long* p, unsigned long long v){
  __hip_atomic_store(p, v, __ATOMIC_RELAXED, __HIP_MEMORY_SCOPE_AGENT);
}

// ---- R21 fused setup kernel (unchanged): blocks 0..63 proto, 64..4159 prep.
__global__ __launch_bounds__(256) void setup_kernel(
    const float* __restrict__ fs, const int* __restrict__ ys,
    float* __restrict__ Pt, float* __restrict__ pn,
    const float* __restrict__ X, float* __restrict__ qn,
    _Float16* __restrict__ Xh, _Float16* __restrict__ Xl)
{
  __shared__ union {
    struct {                                // proto branch
      int   list[N_S];
      int   pref[256];
      int   lcount;
      float red[256];
    } p;
    float red[256];                         // prep branch
  } S;

  const int t = threadIdx.x;

  if (blockIdx.x < N_C){
    // ================= proto =================
    const int c = blockIdx.x;
    int loc[7]; int cnt = 0;
    const int base = t * 7;                  // 256*7 = 1792 >= 1600
    #pragma unroll
    for (int u = 0; u < 7; u++){
      const int i = base + u;
      if (i < N_S && ys[i] == c) loc[cnt++] = i;
    }
    S.p.pref[t] = cnt;
    __syncthreads();
    for (int off = 1; off < 256; off <<= 1){
      int v = (t >= off) ? S.p.pref[t - off] : 0;
      __syncthreads();
      S.p.pref[t] += v;
      __syncthreads();
    }
    const int start = S.p.pref[t] - cnt;
    for (int u = 0; u < cnt; u++) S.p.list[start + u] = loc[u];
    if (t == 255) S.p.lcount = S.p.pref[255];
    __syncthreads();

    const int n = S.p.lcount;
    float a0 = 0.f, a1 = 0.f, a2 = 0.f, a3 = 0.f;
    for (int m = 0; m < n; m++){
      const float* r = fs + (size_t)S.p.list[m] * DIM;
      a0 += r[t]; a1 += r[t + 256]; a2 += r[t + 512]; a3 += r[t + 768];
    }
    const float inv = 1.0f / fmaxf((float)n, 1.0f);
    const float v0 = a0*inv, v1 = a1*inv, v2 = a2*inv, v3 = a3*inv;
    Pt[(t      )*N_C + c] = v0;
    Pt[(t + 256)*N_C + c] = v1;
    Pt[(t + 512)*N_C + c] = v2;
    Pt[(t + 768)*N_C + c] = v3;
    S.p.red[t] = v0*v0 + v1*v1 + v2*v2 + v3*v3;
    __syncthreads();
    for (int o = 128; o; o >>= 1){ if (t < o) S.p.red[t] += S.p.red[t + o]; __syncthreads(); }
    if (t == 0) pn[c] = S.p.red[0];
  } else {
    // ================= prep =================
    const int i = blockIdx.x - N_C;
    const float* r = X + (size_t)i * DIM;
    const float v0 = r[t], v1 = r[t+256], v2 = r[t+512], v3 = r[t+768];
    const size_t b = (size_t)i * DIM;
    _Float16 h0 = (_Float16)v0, h1 = (_Float16)v1, h2 = (_Float16)v2, h3 = (_Float16)v3;
    Xh[b + t      ] = h0; Xl[b + t      ] = (_Float16)(v0 - (float)h0);
    Xh[b + t + 256] = h1; Xl[b + t + 256] = (_Float16)(v1 - (float)h1);
    Xh[b + t + 512] = h2; Xl[b + t + 512] = (_Float16)(v2 - (float)h2);
    Xh[b + t + 768] = h3; Xl[b + t + 768] = (_Float16)(v3 - (float)h3);
    S.red[t] = v0*v0 + v1*v1 + v2*v2 + v3*v3;
    __syncthreads();
    for (int o = 128; o; o >>= 1){ if (t < o) S.red[t] += S.red[t + o]; __syncthreads(); }
    if (t == 0) qn[i] = S.red[0];
  }
}

// ---- av precompute (R23, unchanged): former in-tail P0a, bit-identical.
__global__ __launch_bounds__(1024) void av_kernel(
    const float* __restrict__ Xq, const float* __restrict__ Pt,
    const float* __restrict__ pn, const float* __restrict__ qn,
    float* __restrict__ avb, float* __restrict__ d2min)
{
  __shared__ float pchunk[CHK * N_C];       // 64 KB

  const int tid  = threadIdx.x;
  const int lane = tid & 63;
  const int wv   = tid >> 6;
  const int row  = blockIdx.x * 16 + wv;

  const float* xr = Xq + (size_t)row * DIM;
  const f4*    xr4 = (const f4*)xr;
  float dp[8];
  #pragma unroll
  for (int u = 0; u < 8; u++) dp[u] = 0.f;

  for (int f0 = 0; f0 < DIM; f0 += CHK){
    const f4* srcv = (const f4*)(Pt + (size_t)f0 * N_C);
    f4* dstv = (f4*)pchunk;
    #pragma unroll
    for (int u = 0; u < 4; u++) dstv[tid + u * 1024] = srcv[tid + u * 1024];
    __syncthreads();
    #pragma unroll 1
    for (int f = 0; f < CHK; f += 8){
      const f4 xa = xr4[(f0 + f) >> 2];
      const f4 xb = xr4[((f0 + f) >> 2) + 1];
      const float* pc = pchunk + f * N_C + lane;
      dp[0] = fmaf(xa[0], pc[0      ], dp[0]);
      dp[1] = fmaf(xa[1], pc[N_C    ], dp[1]);
      dp[2] = fmaf(xa[2], pc[N_C * 2], dp[2]);
      dp[3] = fmaf(xa[3], pc[N_C * 3], dp[3]);
      dp[4] = fmaf(xb[0], pc[N_C * 4], dp[4]);
      dp[5] = fmaf(xb[1], pc[N_C * 5], dp[5]);
      dp[6] = fmaf(xb[2], pc[N_C * 6], dp[6]);
      dp[7] = fmaf(xb[3], pc[N_C * 7], dp[7]);
    }
    __syncthreads();
  }
  const float dot = ((dp[0]+dp[1])+(dp[2]+dp[3])) + ((dp[4]+dp[5])+(dp[6]+dp[7]));
  const float av  = fmaxf(qn[row] + pn[lane] - 2.0f * dot, 0.0f);
  avb[row * N_C + lane] = av;
  const float d2m = wave_min64(av);
  if (lane == 0) d2min[row] = d2m;
}

// ---- pairwise distances via f16 split-precision MFMA.
//      R24: 256x256 block tile, 512 threads (8 waves, 2x4), sm=8/sn=4 per
//      wave (same per-wave shape/registers as proven R22). Staging bytes
//      per output 1.5 -> 0.98 (aggregate ~770 -> ~510 MB). Grid 256 blocks,
//      1/CU, LDS 80KB. Per-output MFMA sequence UNCHANGED (k0 ascending,
//      hh/hl/lh pass order, fr/kq lane mapping; staged copies) -> Dq
//      bit-identical. XCD swizzle: 32 blocks/XCD, 2 col-panels each.
__global__ __launch_bounds__(512, 1) void dist_mfma(
    const _Float16* __restrict__ Xh, const _Float16* __restrict__ Xl,
    const float* __restrict__ qn, float* __restrict__ Dq)
{
  __shared__ __align__(16) _Float16 As[2][256][DPAD];  // 40 KB
  __shared__ __align__(16) _Float16 Bs[2][256][DPAD];  // 40 KB

  const int t = threadIdx.x, w = t >> 6, l = t & 63;
  const int lb  = blockIdx.x;              // 256 blocks
  const int xcd = lb & 7, k = lb >> 3;     // k in [0,32)
  const int bxs = xcd * 2 + (k >> 4);      // [0,16) col-panels of 256
  const int bys = k & 15;                  // [0,16) row-panels of 256
  const int bi0 = bys * 256, bj0 = bxs * 256;
  const int i0w = (w >> 2) * 128;          // wave row slice (2 x 128)
  const int j0w = (w & 3) * 64;            // wave col slice (4 x 64)
  const int fr = l & 15;
  const int kq = (l >> 4) * 8;

  // staging: thread t covers row (t>>1), 16-f16 segment (t&1)
  const int srow = t >> 1;                 // [0,256)
  const int sseg = (t & 1) * 16;

  f4 acc[8][4];
  #pragma unroll
  for (int a = 0; a < 8; a++)
    #pragma unroll
    for (int b = 0; b < 4; b++) acc[a][b] = (f4){0.f, 0.f, 0.f, 0.f};

  const size_t abase = (size_t)(bi0 + srow) * DIM + sseg;
  const size_t bbase = (size_t)(bj0 + srow) * DIM + sseg;

  #pragma unroll 1
  for (int k0 = 0; k0 < DIM; k0 += 32){
    // issue all 8 staging loads before the barrier (in flight during wait)
    h8 va0 = *(const h8*)(Xh + abase + k0);
    h8 va1 = *(const h8*)(Xh + abase + k0 + 8);
    h8 vb0 = *(const h8*)(Xl + abase + k0);
    h8 vb1 = *(const h8*)(Xl + abase + k0 + 8);
    h8 vc0 = *(const h8*)(Xh + bbase + k0);
    h8 vc1 = *(const h8*)(Xh + bbase + k0 + 8);
    h8 vd0 = *(const h8*)(Xl + bbase + k0);
    h8 vd1 = *(const h8*)(Xl + bbase + k0 + 8);
    __syncthreads();                      // prev iter's LDS reads complete
    *(h8*)&As[0][srow][sseg    ] = va0;
    *(h8*)&As[0][srow][sseg + 8] = va1;
    *(h8*)&As[1][srow][sseg    ] = vb0;
    *(h8*)&As[1][srow][sseg + 8] = vb1;
    *(h8*)&Bs[0][srow][sseg    ] = vc0;
    *(h8*)&Bs[0][srow][sseg + 8] = vc1;
    *(h8*)&Bs[1][srow][sseg    ] = vd0;
    *(h8*)&Bs[1][srow][sseg + 8] = vd1;
    __syncthreads();                      // tiles ready

    h8 ah[8], al[8];
    #pragma unroll
    for (int sm = 0; sm < 8; sm++){
      ah[sm] = *(const h8*)&As[0][i0w + sm * 16 + fr][kq];
      al[sm] = *(const h8*)&As[1][i0w + sm * 16 + fr][kq];
    }
    #pragma unroll
    for (int sn = 0; sn < 4; sn++){
      h8 bh = *(const h8*)&Bs[0][j0w + sn * 16 + fr][kq];
      h8 bl = *(const h8*)&Bs[1][j0w + sn * 16 + fr][kq];
      #pragma unroll
      for (int sm = 0; sm < 8; sm++){
        acc[sm][sn] = __builtin_amdgcn_mfma_f32_16x16x32_f16(ah[sm], bh, acc[sm][sn], 0, 0, 0);
        acc[sm][sn] = __builtin_amdgcn_mfma_f32_16x16x32_f16(ah[sm], bl, acc[sm][sn], 0, 0, 0);
        acc[sm][sn] = __builtin_amdgcn_mfma_f32_16x16x32_f16(al[sm], bh, acc[sm][sn], 0, 0, 0);
      }
    }
  }

  const int cr = (l >> 4) * 4;
  const int cc = l & 15;
  #pragma unroll
  for (int sm = 0; sm < 8; sm++){
    #pragma unroll
    for (int r = 0; r < 4; r++){
      const int row = bi0 + i0w + sm * 16 + cr + r;
      const float qi = qn[row];
      float* dstrow = &Dq[(size_t)row * N_Q];
      #pragma unroll
      for (int sn = 0; sn < 4; sn++){
        const int col = bj0 + j0w + sn * 16 + cc;
        float d2 = qi + qn[col] - 2.0f * acc[sm][sn][r];
        dstrow[col] = sqrtf(fmaxf(d2, 0.f));
      }
    }
  }
}

// ---- per-row 13 smallest + lambda-median in block N_Q (R23, unchanged).
__global__ __launch_bounds__(256) void topk_kernel(
    const float* __restrict__ Dq, int* __restrict__ nbr,
    float* __restrict__ dnbr, float* __restrict__ sigma,
    const float* __restrict__ d2min, float* __restrict__ denom)
{
  __shared__ int   hist[1024];
  __shared__ float cand[4096];
  __shared__ int   csum[256];
  __shared__ int   candn, b1s, b2s;
  __shared__ float cvf[4 * (KNN + 1)];
  __shared__ int   cif[4 * (KNN + 1)];

  const int i = blockIdx.x, t = threadIdx.x;
  const int lane = t & 63, w = t >> 6;

  if (i < N_Q){
    // ================= topk (R21 body) =================
    const float* row = Dq + (size_t)i * N_Q;
    float r[16];
    #pragma unroll
    for (int u = 0; u < 16; u++) r[u] = row[t + u * 256];

    float keepv = FLT_MAX; int keepi = 0x7fffffff;
    for (int s = 0; s < KNN + 1; s++){
      float best = FLT_MAX; int bj = 0x7fffffff;
      #pragma unroll
      for (int u = 0; u < 16; u++){
        float v = r[u];
        if (v < best){ best = v; bj = t + u * 256; }
      }
      #pragma unroll
      for (int o = 32; o; o >>= 1){
        float ov = __shfl_xor(best, o, 64); int oj = __shfl_xor(bj, o, 64);
        if (ov < best || (ov == best && oj < bj)){ best = ov; bj = oj; }
      }
      if (lane == s){ keepv = best; keepi = bj; }
      if ((bj & 255) == t) r[bj >> 8] = FLT_MAX;
    }
    if (lane < KNN + 1){ cvf[w * (KNN + 1) + lane] = keepv; cif[w * (KNN + 1) + lane] = keepi; }
    __syncthreads();

    if (w == 0){
      float mv = FLT_MAX; int mi = 0x7fffffff;
      if (lane < 4 * (KNN + 1)){ mv = cvf[lane]; mi = cif[lane]; }
      for (int s = 0; s < KNN + 1; s++){
        float best = mv; int bj = mi;
        #pragma unroll
        for (int o = 32; o; o >>= 1){
          float ov = __shfl_xor(best, o, 64); int oj = __shfl_xor(bj, o, 64);
          if (ov < best || (ov == best && oj < bj)){ best = ov; bj = oj; }
        }
        if (lane == 0){
          if (s >= 1){ nbr[i*KNN + s - 1] = bj; dnbr[i*KNN + s - 1] = best; }
          if (s == KNN) sigma[i] = best + 1e-8f;
        }
        if (mi == bj) mv = FLT_MAX;
      }
    }
  } else {
    // ================= lambda-median (256-thread re-lay) =================
    float dv[16];
    int   bidx[16];
    #pragma unroll
    for (int u = 0; u < 16; u++) dv[u] = sqrtf(aload(&d2min[t * 16 + u]));
    float mn = dv[0], mx = dv[0];
    #pragma unroll
    for (int u = 1; u < 16; u++){ mn = fminf(mn, dv[u]); mx = fmaxf(mx, dv[u]); }
    mn = wave_min64(mn); mx = wave_max64(mx);
    if (lane == 0){ cand[w] = mn; cand[w + 4] = mx; }
    __syncthreads();
    if (t == 0){
      float a = cand[0], b = cand[4];
      for (int k = 1; k < 4; k++){ a = fminf(a, cand[k]); b = fmaxf(b, cand[4 + k]); }
      cand[8] = a; cand[9] = b;
    }
    __syncthreads();
    mn = cand[8]; mx = cand[9];
    const float rng = mx - mn;
    const float scale = (rng > 0.f) ? (1024.0f / rng) : 0.f;
    #pragma unroll
    for (int u = 0; u < 4; u++) hist[t * 4 + u] = 0;
    __syncthreads();
    #pragma unroll
    for (int u = 0; u < 16; u++){
      int b = (int)((dv[u] - mn) * scale);
      b = b < 0 ? 0 : (b > 1023 ? 1023 : b);
      bidx[u] = b;
      atomicAdd(&hist[b], 1);
    }
    __syncthreads();
    // inclusive prefix over 1024 bins with 256 threads (exact integer scan)
    int h0 = hist[t*4], h1 = hist[t*4+1], h2 = hist[t*4+2], h3 = hist[t*4+3];
    const int s4 = h0 + h1 + h2 + h3;
    csum[t] = s4;
    __syncthreads();
    for (int off = 1; off < 256; off <<= 1){
      int v = (t >= off) ? csum[t - off] : 0;
      __syncthreads();
      csum[t] += v;
      __syncthreads();
    }
    int run = csum[t] - s4;
    hist[t*4    ] = run + h0;
    hist[t*4 + 1] = run + h0 + h1;
    hist[t*4 + 2] = run + h0 + h1 + h2;
    hist[t*4 + 3] = run + h0 + h1 + h2 + h3;
    __syncthreads();
    #pragma unroll
    for (int u = 0; u < 4; u++){
      const int b = t * 4 + u;
      if (hist[b] >= 2048 && (b == 0 || hist[b - 1] < 2048)) b1s = b;
      if (hist[b] >= 2049 && (b == 0 || hist[b - 1] < 2049)) b2s = b;
    }
    if (t == 0) candn = 0;
    __syncthreads();
    const int b1 = b1s, b2 = b2s;
    const int cntBefore = (b1 > 0) ? hist[b1 - 1] : 0;
    #pragma unroll
    for (int u = 0; u < 16; u++){
      if (bidx[u] >= b1 && bidx[u] <= b2){
        int pos = atomicAdd(&candn, 1);
        cand[pos] = dv[u];
      }
    }
    __syncthreads();
    const int mcnt = candn;
    int P = 2; while (P < mcnt) P <<= 1;
    for (int i2 = mcnt + t; i2 < P; i2 += 256) cand[i2] = FLT_MAX;
    __syncthreads();
    for (int k = 2; k <= P; k <<= 1){
      for (int st = k >> 1; st > 0; st >>= 1){
        for (int i2 = t; i2 < P; i2 += 256){
          int j2 = i2 ^ st;
          if (j2 > i2){
            float a2 = cand[i2], b3 = cand[j2];
            bool up = ((i2 & k) == 0);
            if (up ? (a2 > b3) : (a2 < b3)){ cand[i2] = b3; cand[j2] = a2; }
          }
        }
        __syncthreads();
      }
    }
    if (t == 0){
      float v1 = cand[2047 - cntBefore], v2 = cand[2048 - cntBefore];
      float med = 0.5f * (v1 + v2);
      astore(denom, 2.0f * med * med + 1e-8f);
    }
  }
}

// ============ hierarchical monotonic grid barrier (setup phases only) ============
__device__ __forceinline__ void gbar_leader(int* garr, int* gcnt, int* gen, int target){
  const int g = blockIdx.x >> 4;
  int old = __hip_atomic_fetch_add(&garr[g * 32], 1, __ATOMIC_RELAXED, __HIP_MEMORY_SCOPE_AGENT);
  if ((old & 15) == 15){
    int o2 = __hip_atomic_fetch_add(gcnt, 1, __ATOMIC_RELAXED, __HIP_MEMORY_SCOPE_AGENT);
    if ((o2 & 15) == 15)
      __hip_atomic_fetch_add(gen, 1, __ATOMIC_RELAXED, __HIP_MEMORY_SCOPE_AGENT);
  }
  while (__hip_atomic_load(gen, __ATOMIC_RELAXED, __HIP_MEMORY_SCOPE_AGENT) < target)
    __builtin_amdgcn_s_sleep(1);
}

// ============ packed {phase, delta} flag barrier — contiguous 8B slots ============
__device__ __forceinline__ void pbar_wave0(
    unsigned long long* pslot, int ph, int* sdm, float* sdelta_sh, int lane)
{
  const int par = ph & 1;
  unsigned long long* base = pslot + (size_t)par * NBLK;
  if (lane == 0){
    int myd = sdm[par]; sdm[par] = 0;
    unsigned long long pack =
        ((unsigned long long)(unsigned int)myd << 32) | (unsigned int)ph;
    __builtin_amdgcn_s_waitcnt(0);          // all prior y stores drained
    astore64(&base[blockIdx.x], pack);
  }
  int mx;
  while (1){
    unsigned long long v0 = aload64(&base[lane      ]);
    unsigned long long v1 = aload64(&base[lane +  64]);
    unsigned long long v2 = aload64(&base[lane + 128]);
    unsigned long long v3 = aload64(&base[lane + 192]);
    int f0 = (int)(unsigned int)v0, f1 = (int)(unsigned int)v1;
    int f2 = (int)(unsigned int)v2, f3 = (int)(unsigned int)v3;
    int mn = f0 < f1 ? f0 : f1;
    mn = f2 < mn ? f2 : mn;
    mn = f3 < mn ? f3 : mn;
    if (__all(mn >= ph)){
      int d0 = (int)(v0 >> 32), d1 = (int)(v1 >> 32);
      int d2 = (int)(v2 >> 32), d3 = (int)(v3 >> 32);
      mx = d0 > d1 ? d0 : d1;
      mx = d2 > mx ? d2 : mx;
      mx = d3 > mx ? d3 : mx;
      break;
    }
    __builtin_amdgcn_s_sleep(1);
  }
  #pragma unroll
  for (int o = 32; o; o >>= 1){ int ox = __shfl_xor(mx, o, 64); mx = ox > mx ? ox : mx; }
  if (lane == 0) *sdelta_sh = __int_as_float(mx);
}

// ---- chunked SpMV (R17): K groups of 8 edges, all loads issue concurrently,
//      then the fma sequence runs in the exact old order.
template<int K>
__device__ __forceinline__ void chunk_fma(
    const float* __restrict__ src, const int2* adj, int gbase, int lane,
    float& s0, float& s1, float& s2, float& s3,
    float& s4, float& s5, float& s6, float& s7)
{
  float yv[K][8], wv[K][8];
  #pragma unroll
  for (int g = 0; g < K; g++){
    #pragma unroll
    for (int u = 0; u < 8; u++){
      int2 a = adj[(gbase + g) * 8 + u];
      wv[g][u] = __int_as_float(a.y);
      yv[g][u] = aload(&src[a.x + lane]);
    }
  }
  #pragma unroll
  for (int g = 0; g < K; g++){
    s0 = fmaf(wv[g][0], yv[g][0], s0);
    s1 = fmaf(wv[g][1], yv[g][1], s1);
    s2 = fmaf(wv[g][2], yv[g][2], s2);
    s3 = fmaf(wv[g][3], yv[g][3], s3);
    s4 = fmaf(wv[g][4], yv[g][4], s4);
    s5 = fmaf(wv[g][5], yv[g][5], s5);
    s6 = fmaf(wv[g][6], yv[g][6], s6);
    s7 = fmaf(wv[g][7], yv[g][7], s7);
  }
}

__device__ __forceinline__ float spmv_row(
    const float* __restrict__ src, const int2* adj,
    const int* __restrict__ colA, const float* __restrict__ wA,
    int p0, int p1v, int lane)
{
  const int deg  = p1v - p0;
  const int ncap = deg < ADJ_CAP ? deg : ADJ_CAP;
  const int nfull = ncap & ~7;
  const int ng = nfull >> 3;
  float s0=0.f,s1=0.f,s2=0.f,s3=0.f,s4=0.f,s5=0.f,s6=0.f,s7=0.f;

  int g = 0;
  #pragma unroll 1
  for (; g + 4 <= ng; g += 4){
    chunk_fma<4>(src, adj, g, lane, s0,s1,s2,s3,s4,s5,s6,s7);
  }
  {
    const int left = ng - g;
    if (left == 3)      chunk_fma<3>(src, adj, g, lane, s0,s1,s2,s3,s4,s5,s6,s7);
    else if (left == 2) chunk_fma<2>(src, adj, g, lane, s0,s1,s2,s3,s4,s5,s6,s7);
    else if (left == 1) chunk_fma<1>(src, adj, g, lane, s0,s1,s2,s3,s4,s5,s6,s7);
  }

  if (deg > ADJ_CAP){
    int qg = p0 + ADJ_CAP;
    for (; qg + 8 <= p1v; qg += 8){
      s0 = fmaf(wA[qg    ], aload(&src[colA[qg    ] + lane]), s0);
      s1 = fmaf(wA[qg + 1], aload(&src[colA[qg + 1] + lane]), s1);
      s2 = fmaf(wA[qg + 2], aload(&src[colA[qg + 2] + lane]), s2);
      s3 = fmaf(wA[qg + 3], aload(&src[colA[qg + 3] + lane]), s3);
      s4 = fmaf(wA[qg + 4], aload(&src[colA[qg + 4] + lane]), s4);
      s5 = fmaf(wA[qg + 5], aload(&src[colA[qg + 5] + lane]), s5);
      s6 = fmaf(wA[qg + 6], aload(&src[colA[qg + 6] + lane]), s6);
      s7 = fmaf(wA[qg + 7], aload(&src[colA[qg + 7] + lane]), s7);
    }
    for (; qg < p1v; qg++)
      s0 = fmaf(wA[qg], aload(&src[colA[qg] + lane]), s0);
  } else {
    const int rem = deg - nfull;            // 0..7
    if (rem > 0){
      float yr[7], wr[7];
      #pragma unroll
      for (int u = 0; u < 7; u++){
        if (u < rem){
          int2 a = adj[nfull + u];
          wr[u] = __int_as_float(a.y);
          yr[u] = aload(&src[a.x + lane]);
        }
      }
      #pragma unroll
      for (int u = 0; u < 7; u++)
        if (u < rem) s0 = fmaf(wr[u], yr[u], s0);
    }
  }
  return ((s0+s1)+(s2+s3)) + ((s4+s5)+(s6+s7));
}

// ---- fused tail (R23, unchanged — 222us proven).
__global__ __launch_bounds__(1024, 4) void tail_loop(
    const float* __restrict__ avb,
    const int* __restrict__ nbr, const float* __restrict__ dnbr,
    const float* __restrict__ sigma,
    float* denom, float* wh,
    float* rowsum, int* indeg, int* rowptr, int* fillc,
    int* colA, float* wA, float* buf0, float* buf1,
    unsigned long long* pslot,
    int* gcnt, int* gen, int* garr, int* __restrict__ out)
{
  __shared__ int   sdm[2];
  __shared__ float sdelta;
  __shared__ int   ipart[1024];
  __shared__ int2  adjL[16 * ADJ_CAP];      // 12 KB, per-wave adjacency

  const int tid  = threadIdx.x;
  const int lane = tid & 63;
  const int wv   = tid >> 6;
  const int row  = blockIdx.x * 16 + wv;
  if (tid == 0){ sdm[0] = 0; sdm[1] = 0; }

  // ---------- load av (bit-exact f32 round-trip from av_kernel) ----------
  const float av  = avb[row * N_C + lane];
  const float d2m = wave_min64(av);        // same reduction as before

  // ---------- P0b: edge weights + degrees ----------
  const int e = blockIdx.x * 1024 + tid;
  if (e < N_Q * KNN){
    const int i = e / KNN;
    const int j = nbr[e];
    float wgt = 0.5f * expf(-dnbr[e] / (sigma[i] * sigma[j]));
    astore(&wh[e], wgt);
    atomicAdd(&rowsum[i], wgt);
    atomicAdd(&rowsum[j], wgt);
    atomicAdd(&indeg[j], 1);
  }

  __syncthreads();
  if (tid == 0) gbar_leader(garr, gcnt, gen, 1);
  __syncthreads();

  // ---------- P1: y0 + scan (block 0) ----------
  float xv = -av;
  float m = wave_max64(xv), ee = expf(xv - m), ss = wave_sum64(ee);
  float prev = ee / ss;                    // y0
  astore(&buf0[row * N_C + lane], prev);

  if (blockIdx.x == 0){
    const int base = tid * 4;
    int c0 = aloadi(&indeg[base]),     c1 = aloadi(&indeg[base + 1]);
    int c2 = aloadi(&indeg[base + 2]), c3 = aloadi(&indeg[base + 3]);
    const int s4 = c0 + c1 + c2 + c3;
    ipart[tid] = s4;
    __syncthreads();
    for (int off = 1; off < 1024; off <<= 1){
      int v = (tid >= off) ? ipart[tid - off] : 0;
      __syncthreads();
      ipart[tid] += v;
      __syncthreads();
    }
    int run = ipart[tid] - s4;
    astorei(&rowptr[base    ], KNN * (base    ) + run); run += c0;
    astorei(&rowptr[base + 1], KNN * (base + 1) + run); run += c1;
    astorei(&rowptr[base + 2], KNN * (base + 2) + run); run += c2;
    astorei(&rowptr[base + 3], KNN * (base + 3) + run);
    if (tid == 1023) astorei(&rowptr[N_Q], KNN * N_Q + ipart[1023]);
  }

  __syncthreads();
  if (tid == 0) gbar_leader(garr, gcnt, gen, 2);
  __syncthreads();

  // ---------- P2: CSR fill + per-row coef ----------
  if (e < N_Q * KNN){
    const int i = e / KNN, tt = e % KNN;
    const int j = nbr[e];
    const float wgt = aload(&wh[e]);
    const int p = aloadi(&rowptr[i]) + tt;
    colA[p] = j * N_C; wA[p] = wgt;
    const int q = aloadi(&rowptr[j]) + KNN + atomicAdd(&fillc[j], 1);
    colA[q] = i * N_C; wA[q] = wgt;
  }
  const float cf = expf(-d2m / aload(denom)) / (aload(&rowsum[row]) + 1e-8f);
  const int p0  = aloadi(&rowptr[row]);
  const int p1v = aloadi(&rowptr[row + 1]);

  __builtin_amdgcn_fence(__ATOMIC_RELEASE, "agent");
  __syncthreads();
  if (tid == 0) gbar_leader(garr, gcnt, gen, 3);
  __syncthreads();
  __builtin_amdgcn_fence(__ATOMIC_ACQUIRE, "agent");

  // ---------- preload loop-invariant adjacency into LDS ----------
  {
    const int deg  = p1v - p0;
    const int ncap = deg < ADJ_CAP ? deg : ADJ_CAP;
    for (int u = lane; u < ncap; u += 64)
      adjL[wv * ADJ_CAP + u] = make_int2(colA[p0 + u], __float_as_int(wA[p0 + u]));
  }
  __syncthreads();
  const int2* adj = adjL + wv * ADJ_CAP;

  // ---------- P3: y1 = step(y0); publish delta via pbar phase 1 ----------
  float cur;
  {
    float sum = spmv_row(buf0, adj, colA, wA, p0, p1v, lane);
    float xv2 = -av + cf * sum;
    float mm = wave_max64(xv2), e2 = expf(xv2 - mm), ss2 = wave_sum64(e2);
    cur = e2 / ss2;
    astore(&buf1[row * N_C + lane], cur);
  }
  float dm = wave_max64(fabsf(cur - prev));
  if (lane == 0) atomicMax(&sdm[1], __float_as_int(dm));
  __syncthreads();                         // drains all waves' y stores + LDS
  if (wv == 0) pbar_wave0(pslot, 1, sdm, &sdelta, lane);
  __syncthreads();
  float delta = sdelta;

  // ---------- P4: the while-loop ----------
  int par = 1;                             // buffer currently holding y_new
  for (int t = 0;; t++){
    if (t >= MAX_ITER || delta < EPS_CONV) break;
    const float* src = par ? buf1 : buf0;
    float*       dst = par ? buf0 : buf1;
    float sum = spmv_row(src, adj, colA, wA, p0, p1v, lane);
    float xv2 = -av + cf * sum;
    float mm = wave_max64(xv2), e2 = expf(xv2 - mm), ss2 = wave_sum64(e2);
    float nxt = e2 / ss2;
    astore(&dst[row * N_C + lane], nxt);
    const int ph = t + 2;
    dm = wave_max64(fabsf(nxt - cur));
    if (lane == 0) atomicMax(&sdm[ph & 1], __float_as_int(dm));
    __syncthreads();
    if (wv == 0) pbar_wave0(pslot, ph, sdm, &sdelta, lane);
    __syncthreads();
    delta = sdelta;
    prev = cur; cur = nxt; par ^= 1;
  }

  // argmax of y (prev); first occurrence on ties
  float bv = prev; int bi = lane;
  #pragma unroll
  for (int o = 32; o; o >>= 1){
    float ov = __shfl_xor(bv, o, 64); int oi = __shfl_xor(bi, o, 64);
    if (ov > bv || (ov == bv && oi < bi)){ bv = ov; bi = oi; }
  }
  if (lane == 0) out[row] = bi;
}

extern "C" void kernel_launch(void* const* d_in, const int* in_sizes, int n_in,
                              void* d_out, int out_size, void* d_ws, size_t ws_size,
                              hipStream_t stream)
{
  const float* feat_s = (const float*)d_in[0];
  const int*   y_s    = (const int*)d_in[1];
  const float* feat_q = (const float*)d_in[2];
  int* out = (int*)d_out;

  char* wp = (char*)d_ws;
  auto alloc = [&](size_t bytes) -> char* {
    char* p = wp;
    wp += (bytes + 255) & ~(size_t)255;
    return p;
  };
  float*     Dq  = (float*)alloc((size_t)N_Q * N_Q * 4);     // 64 MB
  _Float16*  Xh  = (_Float16*)alloc((size_t)N_Q * DIM * 2);  // 8 MB
  _Float16*  Xl  = (_Float16*)alloc((size_t)N_Q * DIM * 2);  // 8 MB
  float* Pt     = (float*)alloc((size_t)DIM * N_C * 4);
  float* pn     = (float*)alloc(N_C * 4);
  float* qn     = (float*)alloc(N_Q * 4);
  float* avb    = (float*)alloc((size_t)N_Q * N_C * 4);      // 1 MB
  float* d2min  = (float*)alloc(N_Q * 4);
  float* denom  = (float*)alloc(256);
  int*   nbr    = (int*)alloc((size_t)N_Q * KNN * 4);
  float* dnbr   = (float*)alloc((size_t)N_Q * KNN * 4);
  float* sigma  = (float*)alloc(N_Q * 4);
  float* wh     = (float*)alloc((size_t)N_Q * KNN * 4);
  int*   rowptr = (int*)alloc((N_Q + 1) * 4);
  int*   colA   = (int*)alloc((size_t)2 * N_Q * KNN * 4);
  float* wA     = (float*)alloc((size_t)2 * N_Q * KNN * 4);
  float* buf0   = (float*)alloc((size_t)N_Q * N_C * 4);
  float* buf1   = (float*)alloc((size_t)N_Q * N_C * 4);
  // zero-region: rowsum | indeg | fillc | syncw | garr | pslot (packed, 4KB)
  const size_t zbytes = (size_t)N_Q*12 + 256 + 2048 + 2 * NBLK * 8;
  char*  zbase  = alloc(zbytes);
  float* rowsum = (float*)(zbase);
  int*   indeg  = (int*)(zbase + N_Q*4);
  int*   fillc  = (int*)(zbase + N_Q*8);
  int*   syncw  = (int*)(zbase + N_Q*12);
  int*   garr   = (int*)(zbase + N_Q*12 + 256);
  unsigned long long* pslot = (unsigned long long*)(zbase + N_Q*12 + 256 + 2048);

  hipMemsetAsync(zbase, 0, zbytes, stream);

  setup_kernel <<<N_Q + N_C, 256, 0, stream>>>(feat_s, y_s, Pt, pn, feat_q, qn, Xh, Xl);
  av_kernel    <<<NBLK, 1024, 0, stream>>>(feat_q, Pt, pn, qn, avb, d2min);
  dist_mfma    <<<256, 512, 0, stream>>>(Xh, Xl, qn, Dq);
  topk_kernel  <<<N_Q + 1, 256, 0, stream>>>(Dq, nbr, dnbr, sigma, d2min, denom);

  int* gcnt = &syncw[0];
  int* gen  = &syncw[32];
  void* args[] = {&avb, &nbr, &dnbr, &sigma,
                  &denom, &wh, &rowsum, &indeg, &rowptr, &fillc,
                  &colA, &wA, &buf0, &buf1, &pslot,
                  &gcnt, &gen, &garr, &out};
  hipLaunchCooperativeKernel((void*)tail_loop, dim3(NBLK), dim3(1024), args, 0, stream);
}